// Round 9
// baseline (2681.712 us; speedup 1.0000x reference)
//
#include <hip/hip_runtime.h>

#define T_ 512
#define B_ 64
#define H_ 512
#define G_ 1024  // 2H

typedef _Float16 f16;
typedef _Float16 h2 __attribute__((ext_vector_type(2)));
typedef _Float16 h4 __attribute__((ext_vector_type(4)));
typedef _Float16 f16x8 __attribute__((ext_vector_type(8)));
typedef float f32x4 __attribute__((ext_vector_type(4)));
typedef unsigned long long u64;

#define SPINMAX (1 << 22)

// ---------------- fp16 dot helper: 8 MACs from two uint4s ----------------
__device__ __forceinline__ float dot8_h(uint4 w, uint4 c, float acc) {
    union U { uint4 u; h2 h[4]; };
    U uw; uw.u = w;
    U uc; uc.u = c;
#if defined(__has_builtin) && __has_builtin(__builtin_amdgcn_fdot2)
    acc = __builtin_amdgcn_fdot2(uw.h[0], uc.h[0], acc, false);
    acc = __builtin_amdgcn_fdot2(uw.h[1], uc.h[1], acc, false);
    acc = __builtin_amdgcn_fdot2(uw.h[2], uc.h[2], acc, false);
    acc = __builtin_amdgcn_fdot2(uw.h[3], uc.h[3], acc, false);
#else
#pragma unroll
    for (int i = 0; i < 4; ++i) {
        acc += (float)uw.h[i][0] * (float)uc.h[i][0];
        acc += (float)uw.h[i][1] * (float)uc.h[i][1];
    }
#endif
    return acc;
}

__device__ __forceinline__ float sigm(float x) { return 1.f / (1.f + __expf(-x)); }

// ---- L3 (agent scope) ops — coherent across XCDs (proven R2 path) ----
__device__ __forceinline__ u64 ldA64(const u64* p) {
    return __hip_atomic_load(p, __ATOMIC_RELAXED, __HIP_MEMORY_SCOPE_AGENT);
}
__device__ __forceinline__ void stA32(unsigned* p, unsigned v) {
    __hip_atomic_store(p, v, __ATOMIC_RELAXED, __HIP_MEMORY_SCOPE_AGENT);
}

// ---------------- pack fp32 [512][1024] -> fp16 uint4 [64][1024] (k8-major)
// (used by fallback scan path)
__global__ void pack_fp16(const float* __restrict__ src, uint4* __restrict__ dst) {
    int idx = blockIdx.x * 256 + threadIdx.x;  // 65536 total
    int j  = idx & (G_ - 1);
    int k8 = idx >> 10;
    union U { uint4 u; f16 h[8]; } v;
#pragma unroll
    for (int i = 0; i < 8; ++i)
        v.h[i] = (f16)src[(size_t)(k8 * 8 + i) * G_ + j];
    dst[idx] = v.u;
}

// ---------------- pack fp32 [512][1024] -> fp16 column-major [1024 cols][64 uint4]
__global__ void pack_wcols(const float* __restrict__ src, uint4* __restrict__ dst) {
    int idx = blockIdx.x * 256 + threadIdx.x;  // 65536 = 1024 cols x 64 k2
    int col = idx & 1023, k2 = idx >> 10;      // coalesced loads across cols
    union U { uint4 u; f16 h[8]; } v;
#pragma unroll
    for (int i = 0; i < 8; ++i)
        v.h[i] = (f16)src[(size_t)(k2 * 8 + i) * G_ + col];
    dst[(size_t)col * 64 + k2] = v.u;
}

// ---------------- pack fp32 vector -> fp16 (8 elems/thread) ----------------
__global__ void pack_xf16(const float* __restrict__ src, f16* __restrict__ dst) {
    int idx = blockIdx.x * 256 + threadIdx.x;
    float4 a = ((const float4*)src)[idx * 2];
    float4 b = ((const float4*)src)[idx * 2 + 1];
    f16x8 v = {(f16)a.x, (f16)a.y, (f16)a.z, (f16)a.w,
               (f16)b.x, (f16)b.y, (f16)b.z, (f16)b.w};
    *(f16x8*)&dst[idx * 8] = v;
}

// ---------------- pack fp32 w[512][1024] -> fp16 BT[1024][512] -------------
__global__ void pack_wT(const float* __restrict__ w, f16* __restrict__ bt) {
    int idx = blockIdx.x * 256 + threadIdx.x;  // 524288
    int k = idx & 511, n = idx >> 9;           // coalesced writes along k
    bt[idx] = (f16)w[(size_t)k * G_ + n];
}

// ---------------- MFMA f16 GEMM: C[M,1024] = A[M,512] @ BT^T + bias --------
// (proven R5) 128x128 tile, BK=64, 4 waves (2x2), wave tile 64x64.
__launch_bounds__(256, 2)
__global__ void mfma_gemm(const f16* __restrict__ A, const f16* __restrict__ BT,
                          const float* __restrict__ bias, f16* __restrict__ C) {
    __shared__ __align__(16) f16 aLds[128][64 + 8];
    __shared__ __align__(16) f16 bLds[128][64 + 8];
    const int tid = threadIdx.x;
    const int bm = blockIdx.x, bn = blockIdx.y;
    const int lane = tid & 63, wid = tid >> 6;
    const int wm = wid & 1, wn = wid >> 1;      // wave grid 2x2
    const int fr = lane & 15, fg = lane >> 4;   // frag row/col, k-group

    f32x4 acc[4][4] = {};

    for (int kt = 0; kt < 8; ++kt) {            // K = 512 = 8 x 64
#pragma unroll
        for (int p = 0; p < 4; ++p) {
            int i = p * 256 + tid;
            int row = i >> 3, slot = i & 7;     // 8 x 16B slots per 64-f16 row
            uint4 av = *(const uint4*)&A[((size_t)(bm * 128 + row)) * 512 + kt * 64 + slot * 8];
            uint4 bv = *(const uint4*)&BT[((size_t)(bn * 128 + row)) * 512 + kt * 64 + slot * 8];
            *(uint4*)&aLds[row][slot * 8] = av;
            *(uint4*)&bLds[row][slot * 8] = bv;
        }
        __syncthreads();
#pragma unroll
        for (int kf = 0; kf < 2; ++kf) {        // two K=32 sub-steps
            const int k0 = kf * 32 + fg * 8;
            f16x8 af[4], bf[4];
#pragma unroll
            for (int mi = 0; mi < 4; ++mi)
                af[mi] = *(const f16x8*)&aLds[wm * 64 + mi * 16 + fr][k0];
#pragma unroll
            for (int ni = 0; ni < 4; ++ni)
                bf[ni] = *(const f16x8*)&bLds[wn * 64 + ni * 16 + fr][k0];
#pragma unroll
            for (int mi = 0; mi < 4; ++mi)
#pragma unroll
                for (int ni = 0; ni < 4; ++ni)
                    acc[mi][ni] = __builtin_amdgcn_mfma_f32_16x16x32_f16(
                        af[mi], bf[ni], acc[mi][ni], 0, 0, 0);
        }
        __syncthreads();
    }

#pragma unroll
    for (int mi = 0; mi < 4; ++mi) {
#pragma unroll
        for (int ni = 0; ni < 4; ++ni) {
            int n = bn * 128 + wn * 64 + ni * 16 + fr;
            float bv = bias[n];
#pragma unroll
            for (int r = 0; r < 4; ++r) {
                int m = bm * 128 + wm * 64 + mi * 16 + fg * 4 + r;
                C[(size_t)m * G_ + n] = (f16)(acc[mi][ni][r] + bv);
            }
        }
    }
}

// ---------------- fp32 tiled GEMM (fallback tiers) --------------------------
#define GM 128
#define GN 64
#define GK 16
__launch_bounds__(256)
__global__ void gemm_bias_f16(const float* __restrict__ A,
                              const float* __restrict__ Bm,
                              const float* __restrict__ bias,
                              f16* __restrict__ C, int M) {
    __shared__ __align__(16) float Als[GK][GM + 4];  // transposed A tile
    __shared__ __align__(16) float Bls[GK][GN];
    int tid = threadIdx.x;
    int m_base = blockIdx.x * GM;
    int n_base = blockIdx.y * GN;
    int tx = tid & 15, ty = tid >> 4;
    int m0 = ty * 8, n0 = tx * 4;
    float acc[8][4] = {};

    for (int k0 = 0; k0 < H_; k0 += GK) {
#pragma unroll
        for (int r = 0; r < 2; ++r) {
            int idx2 = tid + 256 * r;
            int row = idx2 >> 2, kc = (idx2 & 3) * 4;
            float4 av = *(const float4*)&A[(size_t)(m_base + row) * H_ + k0 + kc];
            Als[kc + 0][row] = av.x;
            Als[kc + 1][row] = av.y;
            Als[kc + 2][row] = av.z;
            Als[kc + 3][row] = av.w;
        }
        {
            int kk = tid >> 4, colb = (tid & 15) * 4;
            float4 bv = *(const float4*)&Bm[(size_t)(k0 + kk) * G_ + n_base + colb];
            *(float4*)&Bls[kk][colb] = bv;
        }
        __syncthreads();
#pragma unroll
        for (int kk = 0; kk < GK; ++kk) {
            float a0[8], b0[4];
            *(float4*)&a0[0] = *(const float4*)&Als[kk][m0];
            *(float4*)&a0[4] = *(const float4*)&Als[kk][m0 + 4];
            *(float4*)&b0[0] = *(const float4*)&Bls[kk][n0];
#pragma unroll
            for (int im = 0; im < 8; ++im)
#pragma unroll
                for (int in = 0; in < 4; ++in)
                    acc[im][in] += a0[im] * b0[in];
        }
        __syncthreads();
    }
    float bv[4];
    *(float4*)&bv[0] = *(const float4*)&bias[n_base + n0];
#pragma unroll
    for (int im = 0; im < 8; ++im) {
        h4 hv;
#pragma unroll
        for (int in = 0; in < 4; ++in) hv[in] = (f16)(acc[im][in] + bv[in]);
        *(h4*)&C[(size_t)(m_base + m0 + im) * G_ + n_base + n0] = hv;
    }
}

// ---------------- fallback per-batch sequential scan (R1, known-correct) ----
template <int PATH>
__launch_bounds__(1024, 1)
__global__ void ran_scan(const float* __restrict__ x_in, float* __restrict__ x_out,
                         float* __restrict__ c_out, const float* __restrict__ c0,
                         const int* __restrict__ length,
                         const uint4* __restrict__ whh_p,
                         const f16* __restrict__ wi, const float* __restrict__ bias,
                         const float* __restrict__ whh_f, const float* __restrict__ wih_f) {
    __shared__ __align__(16) f16 c_h[H_];
    __shared__ __align__(16) float c_f32[H_];
    __shared__ __align__(16) float x_f32[H_];
    __shared__ float g_i_lds[H_];

    const int b = blockIdx.x, tid = threadIdx.x;
    int len = length[b];
    if (len < 0) len = 0;
    if (len > T_) len = T_;

    float c1 = 0.f;
    if (tid < H_) {
        c1 = c0[(size_t)b * H_ + tid];
        c_h[tid] = (f16)c1;
        if (PATH == 2) c_f32[tid] = c1;
    }
    const float bj = (PATH == 0) ? 0.f : bias[tid];
    __syncthreads();

    for (int t = 0; t < len; ++t) {
        const size_t base = ((size_t)t * B_ + b) * H_;
        float xv = 0.f;
        if (tid < H_) {
            xv = x_in[base + tid];
            if (PATH == 2) x_f32[tid] = xv;
        }
        if (PATH == 2) __syncthreads();

        float g;
        if (PATH == 0) g = (float)wi[((size_t)t * B_ + b) * G_ + tid];
        else           g = bj;

        if (PATH == 0) {
            const uint4* cc = (const uint4*)c_h;
#pragma unroll 4
            for (int k8 = 0; k8 < H_ / 8; ++k8)
                g = dot8_h(whh_p[(size_t)k8 * G_ + tid], cc[k8], g);
        } else {
#pragma unroll 2
            for (int k = 0; k < H_; k += 4) {
                float4 cv = *(const float4*)&c_f32[k];
                g += cv.x * whh_f[(size_t)(k + 0) * G_ + tid];
                g += cv.y * whh_f[(size_t)(k + 1) * G_ + tid];
                g += cv.z * whh_f[(size_t)(k + 2) * G_ + tid];
                g += cv.w * whh_f[(size_t)(k + 3) * G_ + tid];
            }
#pragma unroll 2
            for (int k = 0; k < H_; k += 4) {
                float4 xvv = *(const float4*)&x_f32[k];
                g += xvv.x * wih_f[(size_t)(k + 0) * G_ + tid];
                g += xvv.y * wih_f[(size_t)(k + 1) * G_ + tid];
                g += xvv.z * wih_f[(size_t)(k + 2) * G_ + tid];
                g += xvv.w * wih_f[(size_t)(k + 3) * G_ + tid];
            }
        }

        if (tid >= H_) g_i_lds[tid - H_] = g;
        __syncthreads();
        if (tid < H_) {
            float gi = g_i_lds[tid];
            float c_old = c1;
            c1 = sigm(gi) * xv + sigm(g) * tanhf(c_old);
            c_h[tid] = (f16)c1;
            if (PATH == 2) c_f32[tid] = c1;
            x_out[base + tid] = c1;
        }
        __syncthreads();
    }

    if (tid < H_) {
        for (int t = len; t < T_; ++t)
            x_out[((size_t)t * B_ + b) * H_ + tid] = c1;
        c_out[(size_t)b * H_ + tid] = c1;
    }
}

// ---------------- persistent multi-CU scan, MFMA + in-register finalize ----
// grid = 256 blocks: blockIdx = s*32 + bg.  bg owns batches {2bg, 2bg+1};
// s in [0,8) owns col-pairs [s*64, s*64+64) (f-col j, i-col 512+j).
// R9 vs R7: (a) wave w's B-frag cols 0-7 = f-cols j, cols 8-15 = the MATCHING
// i-cols, so lanes 0-7 hold gf in-register and grab gi via 2x __shfl(lane+8)
// -> finalize fully in-register (g_buf LDS round trip removed); (b) c_h is
// parity-double-buffered -> single barrier per step (mid barrier removed).
// 8-wave MFMA shape kept from R7 (R8 showed 4-wave compute regresses).
// Exchange: unchanged proven L3 tagged-word rendezvous.
__global__ __launch_bounds__(512, 1)
void scan_mfma6(const float* __restrict__ x_in, const f16* __restrict__ wi,
                const uint4* __restrict__ wpack, const float* __restrict__ c0,
                const int* __restrict__ length, float* __restrict__ out,
                float* __restrict__ cn, unsigned* __restrict__ cbuf,
                int base_tag) {
    __shared__ __align__(16) f16 c_h[2][2][H_ + 32];  // [parity][batch][], b1 at +32
    __shared__ float c_fin[2][64];

    const int tid = threadIdx.x;
    const int bg = blockIdx.x & 31, s = blockIdx.x >> 5;
    const int b0 = bg * 2;
    const int w = tid >> 6, lane = tid & 63;
    const int n16 = lane & 15, kg = lane >> 4;      // frag col, k-group

    // ---- B-frag (weights) into registers: wave w col n16 -> G-col ----
    // cols 0-7 = f-cols j (= s*64 + w*8 + n16), cols 8-15 = matching i-cols
    const int jloc = w * 8 + (n16 & 7);             // 0..63
    const int gcol = (n16 < 8) ? (s * 64 + jloc) : (512 + s * 64 + jloc);
    uint4 wreg[16];
    {
        const uint4* wp = wpack + (size_t)gcol * 64 + kg;
#pragma unroll
        for (int m = 0; m < 16; ++m) wreg[m] = wp[m * 4];
    }

    // ---- init c parity 0 (batch1 at +32 f16 -> disjoint bank range) ----
    {
        float a = c0[(size_t)b0 * H_ + tid];
        float b = c0[(size_t)(b0 + 1) * H_ + tid];
        c_h[0][0][tid] = (f16)a;
        c_h[0][1][tid + 32] = (f16)b;
    }
    int len0 = length[b0], len1 = length[b0 + 1];
    len0 = min(max(len0, 0), T_);
    len1 = min(max(len1, 0), T_);
    const int maxlen = max(len0, len1);

    const int ab = (n16 < 1) ? 0 : 1;               // A-frag row -> batch src
    const bool fin = (lane < 8);                    // finalize duty lanes
    const int jj = s * 64 + jloc;                   // this lane's output col
    float c_old0 = 0.f, c_old1 = 0.f;
    if (fin) {
        c_old0 = c0[(size_t)b0 * H_ + jj];
        c_old1 = c0[(size_t)(b0 + 1) * H_ + jj];
    }
    __syncthreads();

    for (int t = 0; t < maxlen; ++t) {
        const int p = t & 1, p1 = p ^ 1;
        // prefetch x / wi (fin lanes; latency hidden under the MFMAs)
        float xv0 = 0.f, xv1 = 0.f, wif0 = 0.f, wif1 = 0.f, wii0 = 0.f, wii1 = 0.f;
        if (fin) {
            size_t r0 = (size_t)t * B_ + b0;
            xv0  = x_in[r0 * H_ + jj];
            xv1  = x_in[(r0 + 1) * H_ + jj];
            wif0 = (float)wi[r0 * G_ + jj];
            wif1 = (float)wi[(r0 + 1) * G_ + jj];
            wii0 = (float)wi[r0 * G_ + 512 + jj];
            wii1 = (float)wi[(r0 + 1) * G_ + 512 + jj];
        }

        // ---- g = c @ W: 16 MFMA per wave, A-frag from c_h[p] ----
        f32x4 acc = {};
        {
            const f16* cb = &c_h[p][ab][ab ? 32 : 0];
#pragma unroll
            for (int m = 0; m < 16; ++m) {
                f16x8 af = *(const f16x8*)(cb + m * 32 + kg * 8);
                acc = __builtin_amdgcn_mfma_f32_16x16x32_f16(
                    af, *(const f16x8*)&wreg[m], acc, 0, 0, 0);
            }
        }
        const unsigned tagw = (unsigned)(base_tag + t + 1) & 0xffffu;

        // gi lives in lane+8 (C-frag regs 0/1 = batches 0/1)
        float gi0 = __shfl(acc[0], lane + 8, 64);
        float gi1 = __shfl(acc[1], lane + 8, 64);

        // ---- finalize in-register (lanes 0-7 of every wave) ----
        if (fin) {
            float gf0 = acc[0] + wif0, gf1 = acc[1] + wif1;
            gi0 += wii0; gi1 += wii1;
            float c1_0, c1_1;
            if (t < len0) {
                float e2 = __expf(2.f * c_old0);
                c1_0 = sigm(gi0) * xv0 + sigm(gf0) * ((e2 - 1.f) / (e2 + 1.f));
            } else c1_0 = c_old0;
            if (t < len1) {
                float e2 = __expf(2.f * c_old1);
                c1_1 = sigm(gi1) * xv1 + sigm(gf1) * ((e2 - 1.f) / (e2 + 1.f));
            } else c1_1 = c_old1;
            c_old0 = c1_0; c_old1 = c1_1;
            union { f16 h; unsigned short u; } v0, v1;
            v0.h = (f16)c1_0; v1.h = (f16)c1_1;
            // publish first (peers spin on this), then local bookkeeping
            stA32(&cbuf[((size_t)(p1 * B_ + b0) << 9) + jj], (tagw << 16) | v0.u);
            stA32(&cbuf[((size_t)(p1 * B_ + b0 + 1) << 9) + jj], (tagw << 16) | v1.u);
            size_t ob = (size_t)t * B_ + b0;
            out[ob * H_ + jj]       = c1_0;
            out[(ob + 1) * H_ + jj] = c1_1;
            c_h[p1][0][jj]      = v0.h;
            c_h[p1][1][jj + 32] = v1.h;
        }

        // ---- exchange: pull peers' c-chunks for step t+1 into c_h[p1] ----
        if (t + 1 < maxlen) {
            int bidx = tid >> 8;
            int e = (tid & 255) * 2;
            if ((unsigned)(e - s * 64) >= 64u) {   // not our own chunk
                const u64 want2 = ((u64)tagw << 48) | ((u64)tagw << 16);
                const u64 mask2 = 0xffff0000ffff0000ull;
                const u64* pb = (const u64*)(cbuf +
                                   ((size_t)(p1 * B_ + b0 + bidx) << 9) + e);
                u64 v = ldA64(pb);
                int gd = 0;
                while ((v & mask2) != want2) {
                    if (++gd > SPINMAX) break;       // safety valve
                    if (gd > 128) __builtin_amdgcn_s_sleep(1);
                    v = ldA64(pb);
                }
                *(unsigned*)&c_h[p1][bidx][e + (bidx ? 32 : 0)] =
                    ((unsigned)v & 0xffffu) | (((unsigned)(v >> 32) & 0xffffu) << 16);
            }
        }
        __syncthreads();
    }

    if (fin) {
        c_fin[0][jloc] = c_old0;
        c_fin[1][jloc] = c_old1;
        cn[(size_t)b0 * H_ + jj]       = c_old0;
        cn[(size_t)(b0 + 1) * H_ + jj] = c_old1;
    }
    __syncthreads();

    // frozen tail: out[t] = c for t in [maxlen, T)
    const int ntail = T_ - maxlen;
    for (int i = tid; i < ntail * 128; i += 512) {
        int tb = i >> 7, cc = i & 127;
        int q = cc >> 6, jl = cc & 63;
        out[((size_t)(maxlen + tb) * B_ + b0 + q) * H_ + s * 64 + jl] =
            c_fin[q][jl];
    }
}

// ---------------- persistent multi-CU scan, VGPR weights (R6, tier-2) ------
__global__ __launch_bounds__(512, 1)
void scan_vgpr(const float* __restrict__ x_in, const f16* __restrict__ wi,
               const uint4* __restrict__ wpack, const float* __restrict__ c0,
               const int* __restrict__ length, float* __restrict__ out,
               float* __restrict__ cn, unsigned* __restrict__ cbuf,
               int base_tag) {
    __shared__ __align__(16) f16 c_h[2][H_];
    __shared__ float red[2][128][5];
    __shared__ float c_fin[2][64];

    const int tid = threadIdx.x;
    const int bg = blockIdx.x & 31, s = blockIdx.x >> 5;
    const int b0 = bg * 2;
    const int col = tid & 127, kq = tid >> 7;

    const int gcol = s * 64 + (col & 63) + ((col >> 6) << 9);
    uint4 wreg[16];
    {
        const uint4* wp = wpack + (size_t)gcol * 64 + kq * 16;
#pragma unroll
        for (int i = 0; i < 16; ++i) wreg[i] = wp[i];
    }

    {
        float a = c0[(size_t)b0 * H_ + tid];
        float b = c0[(size_t)(b0 + 1) * H_ + tid];
        c_h[0][tid] = (f16)a;
        c_h[1][tid] = (f16)b;
    }
    int len0 = length[b0], len1 = length[b0 + 1];
    len0 = min(max(len0, 0), T_);
    len1 = min(max(len1, 0), T_);
    const int maxlen = max(len0, len1);

    const int fb = tid >> 6, fcol = tid & 63;
    const int jj = s * 64 + fcol;
    const int myb = b0 + fb;
    const int mylen = fb ? len1 : len0;
    float c_old = 0.f;
    if (tid < 128) c_old = c0[(size_t)myb * H_ + jj];
    __syncthreads();

    for (int t = 0; t < maxlen; ++t) {
        float xv = 0.f, wif = 0.f, wii = 0.f;
        if (tid < 128) {
            size_t rb = (size_t)t * B_ + myb;
            xv  = x_in[rb * H_ + jj];
            wif = (float)wi[rb * G_ + jj];
            wii = (float)wi[rb * G_ + 512 + jj];
        }

        {
            const uint4* cA = (const uint4*)&c_h[0][0];
            const uint4* cB = (const uint4*)&c_h[1][0];
            const int k20 = kq * 16;
            float a0 = 0.f, a1 = 0.f;
#pragma unroll
            for (int k = 0; k < 16; ++k) {
                uint4 cav = cA[k20 + k];
                uint4 cbv = cB[k20 + k];
                a0 = dot8_h(wreg[k], cav, a0);
                a1 = dot8_h(wreg[k], cbv, a1);
            }
            red[0][col][kq] = a0;
            red[1][col][kq] = a1;
        }
        __syncthreads();

        const int p1 = (t + 1) & 1;
        const unsigned tagw = (unsigned)(base_tag + t + 1) & 0xffffu;

        if (tid < 128) {
            float gf = red[fb][fcol][0] + red[fb][fcol][1] +
                       red[fb][fcol][2] + red[fb][fcol][3] + wif;
            float gi = red[fb][64 + fcol][0] + red[fb][64 + fcol][1] +
                       red[fb][64 + fcol][2] + red[fb][64 + fcol][3] + wii;
            float c1;
            if (t < mylen) {
                float e2 = __expf(2.f * c_old);
                float th = (e2 - 1.f) / (e2 + 1.f);
                c1 = sigm(gi) * xv + sigm(gf) * th;
            } else {
                c1 = c_old;
            }
            c_old = c1;
            union { f16 h; unsigned short u; } cv;
            cv.h = (f16)c1;
            stA32(&cbuf[((size_t)(p1 * B_ + myb) << 9) + jj],
                  (tagw << 16) | (unsigned)cv.u);
            out[((size_t)t * B_ + myb) * H_ + jj] = c1;
            c_h[fb][jj] = cv.h;
        }

        if (t + 1 < maxlen) {
            int bidx = tid >> 8;
            int e = (tid & 255) * 2;
            if ((unsigned)(e - s * 64) >= 64u) {
                const u64 want2 = ((u64)tagw << 48) | ((u64)tagw << 16);
                const u64 mask2 = 0xffff0000ffff0000ull;
                const u64* pb = (const u64*)(cbuf +
                                   ((size_t)(p1 * B_ + b0 + bidx) << 9) + e);
                u64 v = ldA64(pb);
                int gd = 0;
                while ((v & mask2) != want2) {
                    if (++gd > SPINMAX) break;
                    if (gd > 16) __builtin_amdgcn_s_sleep(2);
                    v = ldA64(pb);
                }
                unsigned lo = (unsigned)v & 0xffffu;
                unsigned hi = (unsigned)(v >> 32) & 0xffffu;
                *(unsigned*)&c_h[bidx][e] = lo | (hi << 16);
            }
        }
        __syncthreads();
    }

    if (tid < 128) {
        c_fin[fb][fcol] = c_old;
        cn[(size_t)myb * H_ + jj] = c_old;
    }
    __syncthreads();

    const int ntail = T_ - maxlen;
    for (int i = tid; i < ntail * 128; i += 512) {
        int tb = i >> 7;
        int cc = i & 127;
        int tfb = cc >> 6, tfc = cc & 63;
        out[((size_t)(maxlen + tb) * B_ + b0 + tfb) * H_ + s * 64 + tfc] =
            c_fin[tfb][tfc];
    }
}

// ---------------- host ----------------------------------------------------
extern "C" void kernel_launch(void* const* d_in, const int* in_sizes, int n_in,
                              void* d_out, int out_size, void* d_ws, size_t ws_size,
                              hipStream_t stream) {
    const float* input_ = (const float*)d_in[0];
    const float* hx     = (const float*)d_in[1];
    const int*   length = (const int*)d_in[2];
    const float* w_ih_0 = (const float*)d_in[3];
    const float* w_hh_0 = (const float*)d_in[4];
    const float* b_0    = (const float*)d_in[5];
    const float* w_ih_1 = (const float*)d_in[6];
    const float* w_hh_1 = (const float*)d_in[7];
    const float* b_1    = (const float*)d_in[8];

    float* out = (float*)d_out;
    float* cn  = out + (size_t)T_ * B_ * H_;  // [L,B,H]

    char* wsb = (char*)d_ws;
    const size_t MB = 1u << 20;
    const size_t WI_BYTES = (size_t)T_ * B_ * G_ * sizeof(f16);   // 64 MiB
    const size_t XH_BYTES = (size_t)T_ * B_ * H_ * sizeof(f16);   // 32 MiB
    const int M = T_ * B_;

    // tier 1: [wi 64MB][xh 32MB][wpack 1MB][bt 1MB][cbuf 256KB]
    const size_t need1 = WI_BYTES + XH_BYTES + 2 * MB + 256 * 1024;
    // tier 2: [wi 64MB][wpack 1MB][cbuf 256KB]
    const size_t need2 = WI_BYTES + MB + 256 * 1024;
    // tier 3 (R1 path A)
    const size_t needA = 2 * MB + WI_BYTES;

    if (ws_size >= need1) {
        f16*      wi    = (f16*)wsb;
        f16*      xh    = (f16*)(wsb + WI_BYTES);
        uint4*    wpack = (uint4*)(wsb + WI_BYTES + XH_BYTES);
        f16*      bt    = (f16*)(wsb + WI_BYTES + XH_BYTES + MB);
        unsigned* cbuf  = (unsigned*)(wsb + WI_BYTES + XH_BYTES + 2 * MB);

        hipMemsetAsync(cbuf, 0, 256 * 1024, stream);

        // ---- layer 0 ----
        pack_wcols<<<256, 256, 0, stream>>>(w_hh_0, wpack);
        pack_xf16<<<8192, 256, 0, stream>>>(input_, xh);       // M*512/8/256
        pack_wT<<<2048, 256, 0, stream>>>(w_ih_0, bt);
        mfma_gemm<<<dim3(M / 128, G_ / 128), 256, 0, stream>>>(xh, bt, b_0, wi);
        scan_mfma6<<<256, 512, 0, stream>>>(input_, wi, wpack, hx, length,
                                            out, cn, cbuf, 0);
        // ---- layer 1 ----
        pack_wcols<<<256, 256, 0, stream>>>(w_hh_1, wpack);
        pack_xf16<<<8192, 256, 0, stream>>>(out, xh);
        pack_wT<<<2048, 256, 0, stream>>>(w_ih_1, bt);
        mfma_gemm<<<dim3(M / 128, G_ / 128), 256, 0, stream>>>(xh, bt, b_1, wi);
        scan_mfma6<<<256, 512, 0, stream>>>(out, wi, wpack,
                                            hx + (size_t)B_ * H_, length,
                                            out, cn + (size_t)B_ * H_, cbuf, T_);
    } else if (ws_size >= need2) {
        // tier 2: fp32 GEMM + R6 VGPR-weight scan (proven)
        f16*      wi    = (f16*)wsb;
        uint4*    wpack = (uint4*)(wsb + WI_BYTES);
        unsigned* cbuf  = (unsigned*)(wsb + WI_BYTES + MB);

        hipMemsetAsync(cbuf, 0, 256 * 1024, stream);

        pack_wcols<<<256, 256, 0, stream>>>(w_hh_0, wpack);
        gemm_bias_f16<<<dim3(M / GM, G_ / GN), 256, 0, stream>>>(input_, w_ih_0, b_0, wi, M);
        scan_vgpr<<<256, 512, 0, stream>>>(input_, wi, wpack, hx, length,
                                           out, cn, cbuf, 0);
        pack_wcols<<<256, 256, 0, stream>>>(w_hh_1, wpack);
        gemm_bias_f16<<<dim3(M / GM, G_ / GN), 256, 0, stream>>>(out, w_ih_1, b_1, wi, M);
        scan_vgpr<<<256, 512, 0, stream>>>(out, wi, wpack,
                                           hx + (size_t)B_ * H_, length,
                                           out, cn + (size_t)B_ * H_, cbuf, T_);
    } else if (ws_size >= needA) {
        // tier 3: R1 PATH A
        uint4* whh0 = (uint4*)(wsb + 0 * MB);
        uint4* whh1 = (uint4*)(wsb + 1 * MB);
        f16* wi = (f16*)(wsb + 2 * MB);
        pack_fp16<<<256, 256, 0, stream>>>(w_hh_0, whh0);
        pack_fp16<<<256, 256, 0, stream>>>(w_hh_1, whh1);

        gemm_bias_f16<<<dim3(M / GM, G_ / GN), 256, 0, stream>>>(input_, w_ih_0, b_0, wi, M);
        ran_scan<0><<<64, 1024, 0, stream>>>(input_, out, cn, hx, length,
                                             whh0, wi, b_0, nullptr, nullptr);
        gemm_bias_f16<<<dim3(M / GM, G_ / GN), 256, 0, stream>>>(out, w_ih_1, b_1, wi, M);
        ran_scan<0><<<64, 1024, 0, stream>>>(out, out, cn + (size_t)B_ * H_,
                                             hx + (size_t)B_ * H_, length,
                                             whh1, wi, b_1, nullptr, nullptr);
    } else {
        // tier 4: no workspace — raw fp32 weights, folded projection
        ran_scan<2><<<64, 1024, 0, stream>>>(input_, out, cn, hx, length,
                                             nullptr, nullptr, b_0, w_hh_0, w_ih_0);
        ran_scan<2><<<64, 1024, 0, stream>>>(out, out, cn + (size_t)B_ * H_,
                                             hx + (size_t)B_ * H_, length,
                                             nullptr, nullptr, b_1, w_hh_1, w_ih_1);
    }
}

// Round 10
// 1600.226 us; speedup vs baseline: 1.6758x; 1.6758x over previous
//
#include <hip/hip_runtime.h>

#define T_ 512
#define B_ 64
#define H_ 512
#define G_ 1024  // 2H

typedef _Float16 f16;
typedef _Float16 h2 __attribute__((ext_vector_type(2)));
typedef _Float16 h4 __attribute__((ext_vector_type(4)));
typedef _Float16 f16x8 __attribute__((ext_vector_type(8)));
typedef float f32x4 __attribute__((ext_vector_type(4)));
typedef unsigned long long u64;

#define SPINMAX (1 << 22)

// ---------------- fp16 dot helper: 8 MACs from two uint4s ----------------
__device__ __forceinline__ float dot8_h(uint4 w, uint4 c, float acc) {
    union U { uint4 u; h2 h[4]; };
    U uw; uw.u = w;
    U uc; uc.u = c;
#if defined(__has_builtin) && __has_builtin(__builtin_amdgcn_fdot2)
    acc = __builtin_amdgcn_fdot2(uw.h[0], uc.h[0], acc, false);
    acc = __builtin_amdgcn_fdot2(uw.h[1], uc.h[1], acc, false);
    acc = __builtin_amdgcn_fdot2(uw.h[2], uc.h[2], acc, false);
    acc = __builtin_amdgcn_fdot2(uw.h[3], uc.h[3], acc, false);
#else
#pragma unroll
    for (int i = 0; i < 4; ++i) {
        acc += (float)uw.h[i][0] * (float)uc.h[i][0];
        acc += (float)uw.h[i][1] * (float)uc.h[i][1];
    }
#endif
    return acc;
}

__device__ __forceinline__ float sigm(float x) { return 1.f / (1.f + __expf(-x)); }

// ---- L3 (agent scope) ops — coherent across XCDs (proven R2 path) ----
__device__ __forceinline__ u64 ldA64(const u64* p) {
    return __hip_atomic_load(p, __ATOMIC_RELAXED, __HIP_MEMORY_SCOPE_AGENT);
}
__device__ __forceinline__ void stA32(unsigned* p, unsigned v) {
    __hip_atomic_store(p, v, __ATOMIC_RELAXED, __HIP_MEMORY_SCOPE_AGENT);
}

// ---------------- pack fp32 [512][1024] -> fp16 uint4 [64][1024] (k8-major)
// (used by fallback scan path)
__global__ void pack_fp16(const float* __restrict__ src, uint4* __restrict__ dst) {
    int idx = blockIdx.x * 256 + threadIdx.x;  // 65536 total
    int j  = idx & (G_ - 1);
    int k8 = idx >> 10;
    union U { uint4 u; f16 h[8]; } v;
#pragma unroll
    for (int i = 0; i < 8; ++i)
        v.h[i] = (f16)src[(size_t)(k8 * 8 + i) * G_ + j];
    dst[idx] = v.u;
}

// ---------------- pack fp32 [512][1024] -> fp16 column-major [1024 cols][64 uint4]
__global__ void pack_wcols(const float* __restrict__ src, uint4* __restrict__ dst) {
    int idx = blockIdx.x * 256 + threadIdx.x;  // 65536 = 1024 cols x 64 k2
    int col = idx & 1023, k2 = idx >> 10;      // coalesced loads across cols
    union U { uint4 u; f16 h[8]; } v;
#pragma unroll
    for (int i = 0; i < 8; ++i)
        v.h[i] = (f16)src[(size_t)(k2 * 8 + i) * G_ + col];
    dst[(size_t)col * 64 + k2] = v.u;
}

// ---------------- pack fp32 w[512][1024] -> fp16 BT[1024][512] -------------
__global__ void pack_wT(const float* __restrict__ w, f16* __restrict__ bt) {
    int idx = blockIdx.x * 256 + threadIdx.x;  // 524288
    int k = idx & 511, n = idx >> 9;           // coalesced writes along k
    bt[idx] = (f16)w[(size_t)k * G_ + n];
}

// ---------------- MFMA f16 GEMM, fp32 A: C = A[M,512] @ BT^T + bias --------
// R10: A is read fp32 (input_/out) and converted during LDS staging —
// eliminates the pack_xf16 pass (32MB write + 64MB read per layer).
// Otherwise identical to the R5-proven 128x128 tile, BK=64, 2x2 waves.
__launch_bounds__(256, 2)
__global__ void mfma_gemm_axf32(const float* __restrict__ A, const f16* __restrict__ BT,
                                const float* __restrict__ bias, f16* __restrict__ C) {
    __shared__ __align__(16) f16 aLds[128][64 + 8];
    __shared__ __align__(16) f16 bLds[128][64 + 8];
    const int tid = threadIdx.x;
    const int bm = blockIdx.x, bn = blockIdx.y;
    const int lane = tid & 63, wid = tid >> 6;
    const int wm = wid & 1, wn = wid >> 1;      // wave grid 2x2
    const int fr = lane & 15, fg = lane >> 4;   // frag row/col, k-group

    f32x4 acc[4][4] = {};

    for (int kt = 0; kt < 8; ++kt) {            // K = 512 = 8 x 64
        // ---- A tile: 128 rows x 64 k fp32 -> f16 (2048 float4) ----
#pragma unroll
        for (int p = 0; p < 8; ++p) {
            int i = p * 256 + tid;
            int row = i >> 4, kc = (i & 15) * 4;
            float4 av = *(const float4*)&A[((size_t)(bm * 128 + row)) * 512 + kt * 64 + kc];
            h4 hv = {(f16)av.x, (f16)av.y, (f16)av.z, (f16)av.w};
            *(h4*)&aLds[row][kc] = hv;
        }
        // ---- B tile: 128 rows x 64 k f16 (1024 uint4) ----
#pragma unroll
        for (int p = 0; p < 4; ++p) {
            int i = p * 256 + tid;
            int row = i >> 3, slot = i & 7;
            uint4 bv = *(const uint4*)&BT[((size_t)(bn * 128 + row)) * 512 + kt * 64 + slot * 8];
            *(uint4*)&bLds[row][slot * 8] = bv;
        }
        __syncthreads();
#pragma unroll
        for (int kf = 0; kf < 2; ++kf) {        // two K=32 sub-steps
            const int k0 = kf * 32 + fg * 8;
            f16x8 af[4], bf[4];
#pragma unroll
            for (int mi = 0; mi < 4; ++mi)
                af[mi] = *(const f16x8*)&aLds[wm * 64 + mi * 16 + fr][k0];
#pragma unroll
            for (int ni = 0; ni < 4; ++ni)
                bf[ni] = *(const f16x8*)&bLds[wn * 64 + ni * 16 + fr][k0];
#pragma unroll
            for (int mi = 0; mi < 4; ++mi)
#pragma unroll
                for (int ni = 0; ni < 4; ++ni)
                    acc[mi][ni] = __builtin_amdgcn_mfma_f32_16x16x32_f16(
                        af[mi], bf[ni], acc[mi][ni], 0, 0, 0);
        }
        __syncthreads();
    }

#pragma unroll
    for (int mi = 0; mi < 4; ++mi) {
#pragma unroll
        for (int ni = 0; ni < 4; ++ni) {
            int n = bn * 128 + wn * 64 + ni * 16 + fr;
            float bv = bias[n];
#pragma unroll
            for (int r = 0; r < 4; ++r) {
                int m = bm * 128 + wm * 64 + mi * 16 + fg * 4 + r;
                C[(size_t)m * G_ + n] = (f16)(acc[mi][ni][r] + bv);
            }
        }
    }
}

// ---------------- fp32 tiled GEMM (fallback tiers) --------------------------
#define GM 128
#define GN 64
#define GK 16
__launch_bounds__(256)
__global__ void gemm_bias_f16(const float* __restrict__ A,
                              const float* __restrict__ Bm,
                              const float* __restrict__ bias,
                              f16* __restrict__ C, int M) {
    __shared__ __align__(16) float Als[GK][GM + 4];  // transposed A tile
    __shared__ __align__(16) float Bls[GK][GN];
    int tid = threadIdx.x;
    int m_base = blockIdx.x * GM;
    int n_base = blockIdx.y * GN;
    int tx = tid & 15, ty = tid >> 4;
    int m0 = ty * 8, n0 = tx * 4;
    float acc[8][4] = {};

    for (int k0 = 0; k0 < H_; k0 += GK) {
#pragma unroll
        for (int r = 0; r < 2; ++r) {
            int idx2 = tid + 256 * r;
            int row = idx2 >> 2, kc = (idx2 & 3) * 4;
            float4 av = *(const float4*)&A[(size_t)(m_base + row) * H_ + k0 + kc];
            Als[kc + 0][row] = av.x;
            Als[kc + 1][row] = av.y;
            Als[kc + 2][row] = av.z;
            Als[kc + 3][row] = av.w;
        }
        {
            int kk = tid >> 4, colb = (tid & 15) * 4;
            float4 bv = *(const float4*)&Bm[(size_t)(k0 + kk) * G_ + n_base + colb];
            *(float4*)&Bls[kk][colb] = bv;
        }
        __syncthreads();
#pragma unroll
        for (int kk = 0; kk < GK; ++kk) {
            float a0[8], b0[4];
            *(float4*)&a0[0] = *(const float4*)&Als[kk][m0];
            *(float4*)&a0[4] = *(const float4*)&Als[kk][m0 + 4];
            *(float4*)&b0[0] = *(const float4*)&Bls[kk][n0];
#pragma unroll
            for (int im = 0; im < 8; ++im)
#pragma unroll
                for (int in = 0; in < 4; ++in)
                    acc[im][in] += a0[im] * b0[in];
        }
        __syncthreads();
    }
    float bv[4];
    *(float4*)&bv[0] = *(const float4*)&bias[n_base + n0];
#pragma unroll
    for (int im = 0; im < 8; ++im) {
        h4 hv;
#pragma unroll
        for (int in = 0; in < 4; ++in) hv[in] = (f16)(acc[im][in] + bv[in]);
        *(h4*)&C[(size_t)(m_base + m0 + im) * G_ + n_base + n0] = hv;
    }
}

// ---------------- fallback per-batch sequential scan (R1, known-correct) ----
template <int PATH>
__launch_bounds__(1024, 1)
__global__ void ran_scan(const float* __restrict__ x_in, float* __restrict__ x_out,
                         float* __restrict__ c_out, const float* __restrict__ c0,
                         const int* __restrict__ length,
                         const uint4* __restrict__ whh_p,
                         const f16* __restrict__ wi, const float* __restrict__ bias,
                         const float* __restrict__ whh_f, const float* __restrict__ wih_f) {
    __shared__ __align__(16) f16 c_h[H_];
    __shared__ __align__(16) float c_f32[H_];
    __shared__ __align__(16) float x_f32[H_];
    __shared__ float g_i_lds[H_];

    const int b = blockIdx.x, tid = threadIdx.x;
    int len = length[b];
    if (len < 0) len = 0;
    if (len > T_) len = T_;

    float c1 = 0.f;
    if (tid < H_) {
        c1 = c0[(size_t)b * H_ + tid];
        c_h[tid] = (f16)c1;
        if (PATH == 2) c_f32[tid] = c1;
    }
    const float bj = (PATH == 0) ? 0.f : bias[tid];
    __syncthreads();

    for (int t = 0; t < len; ++t) {
        const size_t base = ((size_t)t * B_ + b) * H_;
        float xv = 0.f;
        if (tid < H_) {
            xv = x_in[base + tid];
            if (PATH == 2) x_f32[tid] = xv;
        }
        if (PATH == 2) __syncthreads();

        float g;
        if (PATH == 0) g = (float)wi[((size_t)t * B_ + b) * G_ + tid];
        else           g = bj;

        if (PATH == 0) {
            const uint4* cc = (const uint4*)c_h;
#pragma unroll 4
            for (int k8 = 0; k8 < H_ / 8; ++k8)
                g = dot8_h(whh_p[(size_t)k8 * G_ + tid], cc[k8], g);
        } else {
#pragma unroll 2
            for (int k = 0; k < H_; k += 4) {
                float4 cv = *(const float4*)&c_f32[k];
                g += cv.x * whh_f[(size_t)(k + 0) * G_ + tid];
                g += cv.y * whh_f[(size_t)(k + 1) * G_ + tid];
                g += cv.z * whh_f[(size_t)(k + 2) * G_ + tid];
                g += cv.w * whh_f[(size_t)(k + 3) * G_ + tid];
            }
#pragma unroll 2
            for (int k = 0; k < H_; k += 4) {
                float4 xvv = *(const float4*)&x_f32[k];
                g += xvv.x * wih_f[(size_t)(k + 0) * G_ + tid];
                g += xvv.y * wih_f[(size_t)(k + 1) * G_ + tid];
                g += xvv.z * wih_f[(size_t)(k + 2) * G_ + tid];
                g += xvv.w * wih_f[(size_t)(k + 3) * G_ + tid];
            }
        }

        if (tid >= H_) g_i_lds[tid - H_] = g;
        __syncthreads();
        if (tid < H_) {
            float gi = g_i_lds[tid];
            float c_old = c1;
            c1 = sigm(gi) * xv + sigm(g) * tanhf(c_old);
            c_h[tid] = (f16)c1;
            if (PATH == 2) c_f32[tid] = c1;
            x_out[base + tid] = c1;
        }
        __syncthreads();
    }

    if (tid < H_) {
        for (int t = len; t < T_; ++t)
            x_out[((size_t)t * B_ + b) * H_ + tid] = c1;
        c_out[(size_t)b * H_ + tid] = c1;
    }
}

// ---------------- persistent multi-CU scan, MFMA dot engine (R7-proven) ----
// grid = 256 blocks: blockIdx = s*32 + bg.  bg owns batches {2bg, 2bg+1};
// s in [0,8) owns col-pairs [s*64, s*64+64) (f-col j, i-col 512+j).
// g = c @ W via MFMA 16x16x32: per wave 16 G-cols, B-frags (W) in 64 VGPRs,
// A-frag (c rows 0/1 = batches) one ds_read_b128 per MFMA from LDS.
// R10 tweak: dual accumulator chains (m 0-7 / 8-15) break the 16-deep MFMA
// dependency chain; fp32 re-association only (absmax unchanged).
// Exchange: proven L3 tagged-word rendezvous, parity dbuf (bit-exact R7).
__global__ __launch_bounds__(512, 1)
void scan_mfma(const float* __restrict__ x_in, const f16* __restrict__ wi,
               const uint4* __restrict__ wpack, const float* __restrict__ c0,
               const int* __restrict__ length, float* __restrict__ out,
               float* __restrict__ cn, unsigned* __restrict__ cbuf,
               int base_tag) {
    __shared__ __align__(16) f16 c_h[2][H_];        // current c, fp16
    __shared__ __align__(16) float2 g_buf[128];     // g[col][batch0,batch1]
    __shared__ float c_fin[2][64];

    const int tid = threadIdx.x;
    const int bg = blockIdx.x & 31, s = blockIdx.x >> 5;
    const int b0 = bg * 2;
    const int w = tid >> 6, lane = tid & 63;
    const int n16 = lane & 15, kg = lane >> 4;      // frag col, k-group

    // ---- B-frag (weights) into registers: 16 uint4 = 64 VGPR ----
    const int gc = w * 16 + n16;                    // block-local G-col 0..127
    const int gcol = (gc < 64) ? (s * 64 + gc) : (512 + s * 64 + (gc - 64));
    uint4 wreg[16];
    {
        const uint4* wp = wpack + (size_t)gcol * 64 + kg;
#pragma unroll
        for (int m = 0; m < 16; ++m) wreg[m] = wp[m * 4];
    }

    // ---- init c (full vector, both batches) ----
    {
        float a = c0[(size_t)b0 * H_ + tid];
        float b = c0[(size_t)(b0 + 1) * H_ + tid];
        c_h[0][tid] = (f16)a;
        c_h[1][tid] = (f16)b;
    }
    int len0 = length[b0], len1 = length[b0 + 1];
    len0 = min(max(len0, 0), T_);
    len1 = min(max(len1, 0), T_);
    const int maxlen = max(len0, len1);

    const int ab = (n16 < 2) ? n16 : 1;             // A-frag row -> batch
    const int fb = tid >> 6, fcol = tid & 63;       // finalize mapping (tid<128)
    const int jj = s * 64 + fcol;
    const int myb = b0 + fb;
    const int mylen = fb ? len1 : len0;
    float c_old = 0.f;
    if (tid < 128) c_old = c0[(size_t)myb * H_ + jj];
    __syncthreads();

    for (int t = 0; t < maxlen; ++t) {
        // prefetch x / wi for own columns (hidden under the MFMAs)
        float xv = 0.f, wif = 0.f, wii = 0.f;
        if (tid < 128) {
            size_t rb = (size_t)t * B_ + myb;
            xv  = x_in[rb * H_ + jj];
            wif = (float)wi[rb * G_ + jj];
            wii = (float)wi[rb * G_ + 512 + jj];
        }

        // ---- g = c @ W via 2x8 MFMA chains; A-frag = c from LDS ----
        {
            f32x4 acc0 = {}, acc1 = {};
#pragma unroll
            for (int m = 0; m < 8; ++m) {
                f16x8 af = *(const f16x8*)&c_h[ab][m * 32 + kg * 8];
                acc0 = __builtin_amdgcn_mfma_f32_16x16x32_f16(
                    af, *(const f16x8*)&wreg[m], acc0, 0, 0, 0);
            }
#pragma unroll
            for (int m = 8; m < 16; ++m) {
                f16x8 af = *(const f16x8*)&c_h[ab][m * 32 + kg * 8];
                acc1 = __builtin_amdgcn_mfma_f32_16x16x32_f16(
                    af, *(const f16x8*)&wreg[m], acc1, 0, 0, 0);
            }
            if (lane < 16)  // rows 0/1 of C-frag = batches 0/1
                g_buf[w * 16 + lane] =
                    make_float2(acc0[0] + acc1[0], acc0[1] + acc1[1]);
        }
        __syncthreads();

        const int p1 = (t + 1) & 1;
        const unsigned tagw = (unsigned)(base_tag + t + 1) & 0xffffu;

        // ---- finalize own 64 column-pairs (tid<128) ----
        if (tid < 128) {
            float2 vf = g_buf[fcol];
            float2 vi = g_buf[64 + fcol];
            float gf = (fb ? vf.y : vf.x) + wif;
            float gi = (fb ? vi.y : vi.x) + wii;
            float c1;
            if (t < mylen) {
                float e2 = __expf(2.f * c_old);          // tanh via exp
                float th = (e2 - 1.f) / (e2 + 1.f);
                c1 = sigm(gi) * xv + sigm(gf) * th;
            } else {
                c1 = c_old;
            }
            c_old = c1;
            union { f16 h; unsigned short u; } cv;
            cv.h = (f16)c1;
            // publish first (peers spin on this), then local bookkeeping
            stA32(&cbuf[((size_t)(p1 * B_ + myb) << 9) + jj],
                  (tagw << 16) | (unsigned)cv.u);
            out[((size_t)t * B_ + myb) * H_ + jj] = c1;
            c_h[fb][jj] = cv.h;
        }

        // ---- exchange: pull peers' c-chunks for step t+1 ----
        if (t + 1 < maxlen) {
            int bidx = tid >> 8;
            int e = (tid & 255) * 2;
            if ((unsigned)(e - s * 64) >= 64u) {   // not our own chunk
                const u64 want2 = ((u64)tagw << 48) | ((u64)tagw << 16);
                const u64 mask2 = 0xffff0000ffff0000ull;
                const u64* pb = (const u64*)(cbuf +
                                   ((size_t)(p1 * B_ + b0 + bidx) << 9) + e);
                u64 v = ldA64(pb);
                int gd = 0;
                while ((v & mask2) != want2) {
                    if (++gd > SPINMAX) break;       // safety valve
                    if (gd > 16) __builtin_amdgcn_s_sleep(2);
                    v = ldA64(pb);
                }
                unsigned lo = (unsigned)v & 0xffffu;
                unsigned hi = (unsigned)(v >> 32) & 0xffffu;
                *(unsigned*)&c_h[bidx][e] = lo | (hi << 16);
            }
        }
        __syncthreads();
    }

    if (tid < 128) {
        c_fin[fb][fcol] = c_old;
        cn[(size_t)myb * H_ + jj] = c_old;
    }
    __syncthreads();

    // frozen tail: out[t] = c for t in [maxlen, T)
    const int ntail = T_ - maxlen;
    for (int i = tid; i < ntail * 128; i += 512) {
        int tb = i >> 7;
        int cc = i & 127;
        int tfb = cc >> 6, tfc = cc & 63;
        out[((size_t)(maxlen + tb) * B_ + b0 + tfb) * H_ + s * 64 + tfc] =
            c_fin[tfb][tfc];
    }
}

// ---------------- persistent multi-CU scan, VGPR weights (R6, tier-2) ------
__global__ __launch_bounds__(512, 1)
void scan_vgpr(const float* __restrict__ x_in, const f16* __restrict__ wi,
               const uint4* __restrict__ wpack, const float* __restrict__ c0,
               const int* __restrict__ length, float* __restrict__ out,
               float* __restrict__ cn, unsigned* __restrict__ cbuf,
               int base_tag) {
    __shared__ __align__(16) f16 c_h[2][H_];
    __shared__ float red[2][128][5];
    __shared__ float c_fin[2][64];

    const int tid = threadIdx.x;
    const int bg = blockIdx.x & 31, s = blockIdx.x >> 5;
    const int b0 = bg * 2;
    const int col = tid & 127, kq = tid >> 7;

    const int gcol = s * 64 + (col & 63) + ((col >> 6) << 9);
    uint4 wreg[16];
    {
        const uint4* wp = wpack + (size_t)gcol * 64 + kq * 16;
#pragma unroll
        for (int i = 0; i < 16; ++i) wreg[i] = wp[i];
    }

    {
        float a = c0[(size_t)b0 * H_ + tid];
        float b = c0[(size_t)(b0 + 1) * H_ + tid];
        c_h[0][tid] = (f16)a;
        c_h[1][tid] = (f16)b;
    }
    int len0 = length[b0], len1 = length[b0 + 1];
    len0 = min(max(len0, 0), T_);
    len1 = min(max(len1, 0), T_);
    const int maxlen = max(len0, len1);

    const int fb = tid >> 6, fcol = tid & 63;
    const int jj = s * 64 + fcol;
    const int myb = b0 + fb;
    const int mylen = fb ? len1 : len0;
    float c_old = 0.f;
    if (tid < 128) c_old = c0[(size_t)myb * H_ + jj];
    __syncthreads();

    for (int t = 0; t < maxlen; ++t) {
        float xv = 0.f, wif = 0.f, wii = 0.f;
        if (tid < 128) {
            size_t rb = (size_t)t * B_ + myb;
            xv  = x_in[rb * H_ + jj];
            wif = (float)wi[rb * G_ + jj];
            wii = (float)wi[rb * G_ + 512 + jj];
        }

        {
            const uint4* cA = (const uint4*)&c_h[0][0];
            const uint4* cB = (const uint4*)&c_h[1][0];
            const int k20 = kq * 16;
            float a0 = 0.f, a1 = 0.f;
#pragma unroll
            for (int k = 0; k < 16; ++k) {
                uint4 cav = cA[k20 + k];
                uint4 cbv = cB[k20 + k];
                a0 = dot8_h(wreg[k], cav, a0);
                a1 = dot8_h(wreg[k], cbv, a1);
            }
            red[0][col][kq] = a0;
            red[1][col][kq] = a1;
        }
        __syncthreads();

        const int p1 = (t + 1) & 1;
        const unsigned tagw = (unsigned)(base_tag + t + 1) & 0xffffu;

        if (tid < 128) {
            float gf = red[fb][fcol][0] + red[fb][fcol][1] +
                       red[fb][fcol][2] + red[fb][fcol][3] + wif;
            float gi = red[fb][64 + fcol][0] + red[fb][64 + fcol][1] +
                       red[fb][64 + fcol][2] + red[fb][64 + fcol][3] + wii;
            float c1;
            if (t < mylen) {
                float e2 = __expf(2.f * c_old);
                float th = (e2 - 1.f) / (e2 + 1.f);
                c1 = sigm(gi) * xv + sigm(gf) * th;
            } else {
                c1 = c_old;
            }
            c_old = c1;
            union { f16 h; unsigned short u; } cv;
            cv.h = (f16)c1;
            stA32(&cbuf[((size_t)(p1 * B_ + myb) << 9) + jj],
                  (tagw << 16) | (unsigned)cv.u);
            out[((size_t)t * B_ + myb) * H_ + jj] = c1;
            c_h[fb][jj] = cv.h;
        }

        if (t + 1 < maxlen) {
            int bidx = tid >> 8;
            int e = (tid & 255) * 2;
            if ((unsigned)(e - s * 64) >= 64u) {
                const u64 want2 = ((u64)tagw << 48) | ((u64)tagw << 16);
                const u64 mask2 = 0xffff0000ffff0000ull;
                const u64* pb = (const u64*)(cbuf +
                                   ((size_t)(p1 * B_ + b0 + bidx) << 9) + e);
                u64 v = ldA64(pb);
                int gd = 0;
                while ((v & mask2) != want2) {
                    if (++gd > SPINMAX) break;
                    if (gd > 16) __builtin_amdgcn_s_sleep(2);
                    v = ldA64(pb);
                }
                unsigned lo = (unsigned)v & 0xffffu;
                unsigned hi = (unsigned)(v >> 32) & 0xffffu;
                *(unsigned*)&c_h[bidx][e] = lo | (hi << 16);
            }
        }
        __syncthreads();
    }

    if (tid < 128) {
        c_fin[fb][fcol] = c_old;
        cn[(size_t)myb * H_ + jj] = c_old;
    }
    __syncthreads();

    const int ntail = T_ - maxlen;
    for (int i = tid; i < ntail * 128; i += 512) {
        int tb = i >> 7;
        int cc = i & 127;
        int tfb = cc >> 6, tfc = cc & 63;
        out[((size_t)(maxlen + tb) * B_ + b0 + tfb) * H_ + s * 64 + tfc] =
            c_fin[tfb][tfc];
    }
}

// ---------------- host ----------------------------------------------------
extern "C" void kernel_launch(void* const* d_in, const int* in_sizes, int n_in,
                              void* d_out, int out_size, void* d_ws, size_t ws_size,
                              hipStream_t stream) {
    const float* input_ = (const float*)d_in[0];
    const float* hx     = (const float*)d_in[1];
    const int*   length = (const int*)d_in[2];
    const float* w_ih_0 = (const float*)d_in[3];
    const float* w_hh_0 = (const float*)d_in[4];
    const float* b_0    = (const float*)d_in[5];
    const float* w_ih_1 = (const float*)d_in[6];
    const float* w_hh_1 = (const float*)d_in[7];
    const float* b_1    = (const float*)d_in[8];

    float* out = (float*)d_out;
    float* cn  = out + (size_t)T_ * B_ * H_;  // [L,B,H]

    char* wsb = (char*)d_ws;
    const size_t MB = 1u << 20;
    const size_t WI_BYTES = (size_t)T_ * B_ * G_ * sizeof(f16);   // 64 MiB
    const int M = T_ * B_;

    // tier 1: [wi 64MB][wpack 1MB][bt 1MB][cbuf 256KB]
    const size_t need1 = WI_BYTES + 2 * MB + 256 * 1024;
    // tier 3 (R1 path A)
    const size_t needA = 2 * MB + WI_BYTES;

    if (ws_size >= need1) {
        f16*      wi    = (f16*)wsb;
        uint4*    wpack = (uint4*)(wsb + WI_BYTES);
        f16*      bt    = (f16*)(wsb + WI_BYTES + MB);
        unsigned* cbuf  = (unsigned*)(wsb + WI_BYTES + 2 * MB);

        hipMemsetAsync(cbuf, 0, 256 * 1024, stream);

        // ---- layer 0 ----
        pack_wcols<<<256, 256, 0, stream>>>(w_hh_0, wpack);
        pack_wT<<<2048, 256, 0, stream>>>(w_ih_0, bt);
        mfma_gemm_axf32<<<dim3(M / 128, G_ / 128), 256, 0, stream>>>(input_, bt, b_0, wi);
        scan_mfma<<<256, 512, 0, stream>>>(input_, wi, wpack, hx, length,
                                           out, cn, cbuf, 0);
        // ---- layer 1 ----
        pack_wcols<<<256, 256, 0, stream>>>(w_hh_1, wpack);
        pack_wT<<<2048, 256, 0, stream>>>(w_ih_1, bt);
        mfma_gemm_axf32<<<dim3(M / 128, G_ / 128), 256, 0, stream>>>(out, bt, b_1, wi);
        scan_mfma<<<256, 512, 0, stream>>>(out, wi, wpack,
                                           hx + (size_t)B_ * H_, length,
                                           out, cn + (size_t)B_ * H_, cbuf, T_);
    } else if (ws_size >= needA) {
        // tier 3: R1 PATH A
        uint4* whh0 = (uint4*)(wsb + 0 * MB);
        uint4* whh1 = (uint4*)(wsb + 1 * MB);
        f16* wi = (f16*)(wsb + 2 * MB);
        pack_fp16<<<256, 256, 0, stream>>>(w_hh_0, whh0);
        pack_fp16<<<256, 256, 0, stream>>>(w_hh_1, whh1);

        gemm_bias_f16<<<dim3(M / GM, G_ / GN), 256, 0, stream>>>(input_, w_ih_0, b_0, wi, M);
        ran_scan<0><<<64, 1024, 0, stream>>>(input_, out, cn, hx, length,
                                             whh0, wi, b_0, nullptr, nullptr);
        gemm_bias_f16<<<dim3(M / GM, G_ / GN), 256, 0, stream>>>(out, w_ih_1, b_1, wi, M);
        ran_scan<0><<<64, 1024, 0, stream>>>(out, out, cn + (size_t)B_ * H_,
                                             hx + (size_t)B_ * H_, length,
                                             whh1, wi, b_1, nullptr, nullptr);
    } else {
        // tier 4: no workspace — raw fp32 weights, folded projection
        ran_scan<2><<<64, 1024, 0, stream>>>(input_, out, cn, hx, length,
                                             nullptr, nullptr, b_0, w_hh_0, w_ih_0);
        ran_scan<2><<<64, 1024, 0, stream>>>(out, out, cn + (size_t)B_ * H_,
                                             hx + (size_t)B_ * H_, length,
                                             nullptr, nullptr, b_1, w_hh_1, w_ih_1);
    }
}